// Round 23
// baseline (34.549 us; speedup 1.0000x reference)
//
#include <hip/hip_runtime.h>

#define SEQ 8192
#define DM 64

typedef __bf16 bfrag __attribute__((ext_vector_type(8)));   // MFMA A/B operand
typedef __bf16 b4v   __attribute__((ext_vector_type(4)));   // 8-byte bf16 pack
typedef float  f4    __attribute__((ext_vector_type(4)));   // MFMA C/D operand

union PW { int w[4]; bfrag v; };

// fold 1/sqrt(64) * log2(e) into Q so softmax is a bare v_exp_f32 (2^x)
#define QSCALE 0.1803368801111204f

__device__ inline float fexp2(float x) {        // guaranteed native v_exp_f32
    float y;
    asm("v_exp_f32 %0, %1" : "=v"(y) : "v"(x));
    return y;
}

__device__ inline int cvtpk(float a, float b) { // packed 2xbf16 in one instr
    int d;
    asm("v_cvt_pk_bf16_f32 %0, %1, %2" : "=v"(d) : "v"(a), "v"(b));
    return d;
}

// split f32 x8 into bf16 hi + bf16 lo (residual) for near-fp32 MFMA matmul
__device__ inline void split8(const float* __restrict__ p, bfrag& hi, bfrag& lo) {
    #pragma unroll
    for (int e = 0; e < 8; ++e) {
        const float v = p[e];
        const __bf16 h = (__bf16)v;
        hi[e] = h;
        lo[e] = (__bf16)(v - (float)h);
    }
}

// ---------------------------------------------------------------------------
// Kernel 1 (MFMA): MERGED-m tasks (r22-verified, unchanged). 2048 wave-tasks
// = (16-row x-tile rt, dt); 512 blocks x 4 waves; each wave splits x once
// and serves Q, K, V.
// ---------------------------------------------------------------------------
__global__ __launch_bounds__(256) void qkv_proj(
    const float* __restrict__ x,
    const float* __restrict__ wq, const float* __restrict__ bq,
    const float* __restrict__ wk, const float* __restrict__ bk,
    const float* __restrict__ wv, const float* __restrict__ bv,
    __bf16* __restrict__ Qb, __bf16* __restrict__ Ks, __bf16* __restrict__ Vg)
{
    const int lane = threadIdx.x & 63;
    const int wid  = threadIdx.x >> 6;
    const int task = blockIdx.x * 4 + wid;      // 0..2047
    const int rt   = task >> 2;                 // 0..511
    const int dt   = task & 3;                  // 0..3
    const int rb   = rt << 4;
    const int g = lane >> 4, r = lane & 15;

    bfrag xhi[2], xlo[2];                       // shared across all 3 matrices
    #pragma unroll
    for (int kh = 0; kh < 2; ++kh)
        split8(x + (rb + r) * DM + kh * 32 + g * 8, xhi[kh], xlo[kh]);

    #pragma unroll
    for (int m = 0; m < 2; ++m) {               // Q (m=0), K (m=1): mfma(W, X)
        const float* w    = m ? wk : wq;
        const float* bias = m ? bk : bq;
        bfrag whi[2], wlo[2];
        #pragma unroll
        for (int kh = 0; kh < 2; ++kh)
            split8(w + (dt * 16 + r) * DM + kh * 32 + g * 8, whi[kh], wlo[kh]);
        f4 acc = {0.f, 0.f, 0.f, 0.f};
        #pragma unroll
        for (int kh = 0; kh < 2; ++kh) {
            acc = __builtin_amdgcn_mfma_f32_16x16x32_bf16(whi[kh], xhi[kh], acc, 0, 0, 0);
            acc = __builtin_amdgcn_mfma_f32_16x16x32_bf16(wlo[kh], xhi[kh], acc, 0, 0, 0);
            acc = __builtin_amdgcn_mfma_f32_16x16x32_bf16(whi[kh], xlo[kh], acc, 0, 0, 0);
        }
        const int c0 = dt * 16 + g * 4;         // 4 consecutive features
        const float4 b4 = *(const float4*)(bias + c0);
        const float sc = (m == 0) ? QSCALE : 1.0f;
        b4v pv;
        pv[0] = (__bf16)((acc[0] + b4.x) * sc);
        pv[1] = (__bf16)((acc[1] + b4.y) * sc);
        pv[2] = (__bf16)((acc[2] + b4.z) * sc);
        pv[3] = (__bf16)((acc[3] + b4.w) * sc);
        if (m == 0) {
            *(b4v*)(Qb + (rb + r) * DM + c0) = pv;
        } else {
            const int row = rb + r, t = row >> 5, row32 = row & 31;
            const int ch  = dt * 2 + (g >> 1);
            const int b2  = ((row32 >> 4) << 1) | (ch >> 2);
            *(b4v*)(Ks + t * 2048 + b2 * 512 + (ch & 3) * 128
                       + (row32 & 15) * 8 + (g & 1) * 4) = pv;
        }
    }

    {                                           // V (m=2): mfma(X, W)
        bfrag whi[2], wlo[2];
        #pragma unroll
        for (int kh = 0; kh < 2; ++kh)
            split8(wv + (dt * 16 + r) * DM + kh * 32 + g * 8, whi[kh], wlo[kh]);
        f4 acc = {0.f, 0.f, 0.f, 0.f};
        #pragma unroll
        for (int kh = 0; kh < 2; ++kh) {
            acc = __builtin_amdgcn_mfma_f32_16x16x32_bf16(xhi[kh], whi[kh], acc, 0, 0, 0);
            acc = __builtin_amdgcn_mfma_f32_16x16x32_bf16(xlo[kh], whi[kh], acc, 0, 0, 0);
            acc = __builtin_amdgcn_mfma_f32_16x16x32_bf16(xhi[kh], wlo[kh], acc, 0, 0, 0);
        }
        const int d  = dt * 16 + r;
        const float bd = bv[d];
        const int L0 = (rb & 31) + g * 4;
        const int P0 = ((L0 & 15) >> 2) * 8 + (L0 >> 4) * 4;
        const int t  = rb >> 5;
        b4v pv;
        pv[0] = (__bf16)(acc[0] + bd);
        pv[1] = (__bf16)(acc[1] + bd);
        pv[2] = (__bf16)(acc[2] + bd);
        pv[3] = (__bf16)(acc[3] + bd);
        *(b4v*)(Vg + t * 2048 + (d >> 4) * 512 + (P0 >> 3) * 128
                   + (d & 15) * 8 + (P0 & 7)) = pv;
    }
}

// ---------------------------------------------------------------------------
// Kernel 2: flash attention partials — 2 kv-slices x 8 waves/block.
// Grid 512 = fam(0..255, 4-way balanced qt map) x slice(0..1). Wave w covers
// tile residues slice*8+w (mod 16): per-wave work identical to r14/r22
// (stride-16 list, same register footprint, no spill). Occupancy unchanged
// (2 blocks/CU x 8 waves = 4 waves/SIMD). Epilogue: two-pass 8-wave combine
// in 34.8 KB LDS -> Opart[2] (4 MB total, HALF of r22's partial traffic).
// ---------------------------------------------------------------------------
__global__ __launch_bounds__(512)
__attribute__((amdgpu_waves_per_eu(4)))
void flash_attn(
    const __bf16* __restrict__ Qb, const __bf16* __restrict__ Ks,
    const __bf16* __restrict__ Vg,
    float* __restrict__ Opart, float* __restrict__ Lpart)
{
    __shared__ float Ol[4][32][66];          // 33792 B
    __shared__ float Lsm[8][32];             // 1 KB

    const int tid  = threadIdx.x;
    const int lane = tid & 63;
    const int wid  = tid >> 6;               // 0..7
    const int b    = blockIdx.x;
    const int fam  = b >> 1;                 // 0..255
    const int slice = b & 1;                 // kv slice
    const int grp  = fam >> 6, hh = fam & 63;
    const int qt   = (grp == 0) ? (255 - hh) : (grp == 1) ? hh
                   : (grp == 2) ? (191 - hh) : (64 + hh);   // 4-way balanced
    const int qbase = qt * 32;
    const int gq = lane >> 4;                // 0..3
    const int r  = lane & 15;
    const int lo16 = lane << 4;

    bfrag qf[2][2];
    #pragma unroll
    for (int sub = 0; sub < 2; ++sub)
        #pragma unroll
        for (int kh = 0; kh < 2; ++kh)
            qf[sub][kh] = *(const bfrag*)(Qb + (qbase + sub * 16 + r) * DM + kh * 32 + gq * 8);

    bfrag ones;                              // B-operand of the row-sum MFMA
    #pragma unroll
    for (int e = 0; e < 8; ++e) ones[e] = (__bf16)1.0f;

    f4 o[2][4] = {};
    f4 lsacc[2] = {};                        // row-sums via MFMA (all cols equal)

    const char* Kbb = (const char*)Ks;
    const char* Vbb = (const char*)Vg;

    const int jw = slice * 8 + wid;          // this wave's first tile (0..15)
    const int nlive = (qt >= jw) ? ((qt - jw) >> 4) + 1 : 0;

    for (int s = 0; s < nlive; ++s) {
        const int j = jw + s * 16;           // uniform per wave, always live
        const long long jb = (long long)j * 4096;
        const bfrag kf0 = *(const bfrag*)(Kbb + jb + lo16);
        const bfrag kf1 = *(const bfrag*)(Kbb + jb + 1024 + lo16);
        const bfrag kf2 = *(const bfrag*)(Kbb + jb + 2048 + lo16);
        const bfrag kf3 = *(const bfrag*)(Kbb + jb + 3072 + lo16);
        bfrag vf[4];
        #pragma unroll
        for (int dt = 0; dt < 4; ++dt)
            vf[dt] = *(const bfrag*)(Vbb + jb + dt * 1024 + lo16);

        const int kvb = j * 32 + gq * 4;
        #pragma unroll
        for (int sub = 0; sub < 2; ++sub) {
            f4 sh0 = {}, sh1 = {};           // S'[kv][q], swapped operands
            sh0 = __builtin_amdgcn_mfma_f32_16x16x32_bf16(kf0, qf[sub][0], sh0, 0, 0, 0);
            sh0 = __builtin_amdgcn_mfma_f32_16x16x32_bf16(kf1, qf[sub][1], sh0, 0, 0, 0);
            sh1 = __builtin_amdgcn_mfma_f32_16x16x32_bf16(kf2, qf[sub][0], sh1, 0, 0, 0);
            sh1 = __builtin_amdgcn_mfma_f32_16x16x32_bf16(kf3, qf[sub][1], sh1, 0, 0, 0);

            float p0[4], p1[4];
            if (j < qt) {                    // interior tile: bare exp
                #pragma unroll
                for (int e = 0; e < 4; ++e) {
                    p0[e] = fexp2(sh0[e]);
                    p1[e] = fexp2(sh1[e]);
                }
            } else {                         // diagonal tile: per-element kv<=q
                const int qg = qbase + sub * 16 + r;
                #pragma unroll
                for (int e = 0; e < 4; ++e) {
                    p0[e] = (kvb + e      <= qg) ? fexp2(sh0[e]) : 0.f;
                    p1[e] = (kvb + e + 16 <= qg) ? fexp2(sh1[e]) : 0.f;
                }
            }

            PW pu;                           // sigma pack: slots 0-3 <- h0, 4-7 <- h1
            pu.w[0] = cvtpk(p0[0], p0[1]); pu.w[1] = cvtpk(p0[2], p0[3]);
            pu.w[2] = cvtpk(p1[0], p1[1]); pu.w[3] = cvtpk(p1[2], p1[3]);

            lsacc[sub] = __builtin_amdgcn_mfma_f32_16x16x32_bf16(pu.v, ones, lsacc[sub], 0, 0, 0);
            #pragma unroll
            for (int dt = 0; dt < 4; ++dt)
                o[sub][dt] = __builtin_amdgcn_mfma_f32_16x16x32_bf16(pu.v, vf[dt], o[sub][dt], 0, 0, 0);
        }
    }

    // ---- epilogue: two-pass 8-wave combine -> slice partials ----
    if (r == 0)
        #pragma unroll
        for (int sub = 0; sub < 2; ++sub)
            #pragma unroll
            for (int e = 0; e < 4; ++e)
                Lsm[wid][sub * 16 + gq * 4 + e] = lsacc[sub][e];

    if (wid < 4) {                           // pass 1: waves 0-3 write
        #pragma unroll
        for (int sub = 0; sub < 2; ++sub)
            #pragma unroll
            for (int dt = 0; dt < 4; ++dt)
                #pragma unroll
                for (int e = 0; e < 4; ++e)
                    Ol[wid][sub * 16 + gq * 4 + e][dt * 16 + r] = o[sub][dt][e];
    }
    __syncthreads();
    if (wid >= 4) {                          // pass 2: waves 4-7 add (disjoint)
        #pragma unroll
        for (int sub = 0; sub < 2; ++sub)
            #pragma unroll
            for (int dt = 0; dt < 4; ++dt)
                #pragma unroll
                for (int e = 0; e < 4; ++e)
                    Ol[wid - 4][sub * 16 + gq * 4 + e][dt * 16 + r] += o[sub][dt][e];
    }
    __syncthreads();

    for (int i = tid; i < 32 * 64; i += 512) {
        const int row = i >> 6, col = i & 63;
        const float sum = (Ol[0][row][col] + Ol[1][row][col])
                        + (Ol[2][row][col] + Ol[3][row][col]);
        Opart[((long long)slice * SEQ + qbase + row) * DM + col] = sum;
    }
    if (tid < 32) {
        const float l = ((Lsm[0][tid] + Lsm[1][tid]) + (Lsm[2][tid] + Lsm[3][tid]))
                      + ((Lsm[4][tid] + Lsm[5][tid]) + (Lsm[6][tid] + Lsm[7][tid]));
        Lpart[slice * SEQ + qbase + tid] = l;
    }
}

// ---------------------------------------------------------------------------
// Kernel 3: out = (O0+O1) / (L0+L1)
// ---------------------------------------------------------------------------
__global__ __launch_bounds__(256) void normalize(
    const float* __restrict__ Opart, const float* __restrict__ Lpart,
    float* __restrict__ out)
{
    const int i = blockIdx.x * 256 + threadIdx.x;     // f4 index
    const f4* O = (const f4*)Opart;
    const int N = SEQ * DM / 4;
    const int row = i >> 4;
    const f4 a0 = O[i], a1 = O[N + i];
    const float inv = 1.0f / (Lpart[row] + Lpart[SEQ + row]);
    f4 res;
    #pragma unroll
    for (int e = 0; e < 4; ++e) res[e] = (a0[e] + a1[e]) * inv;
    ((f4*)out)[i] = res;
}

extern "C" void kernel_launch(void* const* d_in, const int* in_sizes, int n_in,
                              void* d_out, int out_size, void* d_ws, size_t ws_size,
                              hipStream_t stream)
{
    (void)in_sizes; (void)n_in; (void)out_size; (void)ws_size;
    const float* x  = (const float*)d_in[0];
    const float* wq = (const float*)d_in[1];
    const float* bq = (const float*)d_in[2];
    const float* wk = (const float*)d_in[3];
    const float* bk = (const float*)d_in[4];
    const float* wv = (const float*)d_in[5];
    const float* bv = (const float*)d_in[6];
    float* out = (float*)d_out;

    __bf16* Qb = (__bf16*)d_ws;                       // [S][64] bf16, 1 MB
    __bf16* Ks = Qb + SEQ * DM;                       // tile-major K, 1 MB
    __bf16* Vg = Ks + SEQ * DM;                       // tile-major sigma V, 1 MB
    float*  Opart = (float*)(Vg + SEQ * DM);          // [2][S][64] f32, 4 MB
    float*  Lpart = Opart + 2 * SEQ * DM;             // [2][S] f32, 64 KB

    qkv_proj<<<512, 256, 0, stream>>>(x, wq, bq, wk, bk, wv, bv, Qb, Ks, Vg);
    flash_attn<<<512, 512, 0, stream>>>(Qb, Ks, Vg, Opart, Lpart);
    normalize<<<SEQ * DM / 4 / 256, 256, 0, stream>>>(Opart, Lpart, out);
}

// Round 24
// 32.472 us; speedup vs baseline: 1.0640x; 1.0640x over previous
//
#include <hip/hip_runtime.h>

#define SEQ 8192
#define DM 64

typedef __bf16 bfrag __attribute__((ext_vector_type(8)));   // MFMA A/B operand
typedef __bf16 b4v   __attribute__((ext_vector_type(4)));   // 8-byte bf16 pack
typedef float  f4    __attribute__((ext_vector_type(4)));   // MFMA C/D operand

union PW { int w[4]; bfrag v; };

// fold 1/sqrt(64) * log2(e) into Q so softmax is a bare v_exp_f32 (2^x)
#define QSCALE 0.1803368801111204f

__device__ inline float fexp2(float x) {        // guaranteed native v_exp_f32
    float y;
    asm("v_exp_f32 %0, %1" : "=v"(y) : "v"(x));
    return y;
}

__device__ inline int cvtpk(float a, float b) { // packed 2xbf16 in one instr
    int d;
    asm("v_cvt_pk_bf16_f32 %0, %1, %2" : "=v"(d) : "v"(a), "v"(b));
    return d;
}

// split f32 x8 into bf16 hi + bf16 lo (residual) for near-fp32 MFMA matmul
__device__ inline void split8(const float* __restrict__ p, bfrag& hi, bfrag& lo) {
    #pragma unroll
    for (int e = 0; e < 8; ++e) {
        const float v = p[e];
        const __bf16 h = (__bf16)v;
        hi[e] = h;
        lo[e] = (__bf16)(v - (float)h);
    }
}

// ---------------------------------------------------------------------------
// Kernel 1 (MFMA): MERGED-m tasks (r22-verified best). 2048 wave-tasks =
// (16-row x-tile rt, dt); 512 blocks x 4 waves. Each wave splits x ONCE and
// serves Q, K, V (3x fewer x loads; three independent m-chains for ILP).
// ---------------------------------------------------------------------------
__global__ __launch_bounds__(256) void qkv_proj(
    const float* __restrict__ x,
    const float* __restrict__ wq, const float* __restrict__ bq,
    const float* __restrict__ wk, const float* __restrict__ bk,
    const float* __restrict__ wv, const float* __restrict__ bv,
    __bf16* __restrict__ Qb, __bf16* __restrict__ Ks, __bf16* __restrict__ Vg)
{
    const int lane = threadIdx.x & 63;
    const int wid  = threadIdx.x >> 6;
    const int task = blockIdx.x * 4 + wid;      // 0..2047
    const int rt   = task >> 2;                 // 0..511
    const int dt   = task & 3;                  // 0..3
    const int rb   = rt << 4;
    const int g = lane >> 4, r = lane & 15;

    bfrag xhi[2], xlo[2];                       // shared across all 3 matrices
    #pragma unroll
    for (int kh = 0; kh < 2; ++kh)
        split8(x + (rb + r) * DM + kh * 32 + g * 8, xhi[kh], xlo[kh]);

    // ---- Q (m=0), K (m=1): mfma(W, X) -> D[feat][x-row] ----
    #pragma unroll
    for (int m = 0; m < 2; ++m) {
        const float* w    = m ? wk : wq;
        const float* bias = m ? bk : bq;
        bfrag whi[2], wlo[2];
        #pragma unroll
        for (int kh = 0; kh < 2; ++kh)
            split8(w + (dt * 16 + r) * DM + kh * 32 + g * 8, whi[kh], wlo[kh]);
        f4 acc = {0.f, 0.f, 0.f, 0.f};
        #pragma unroll
        for (int kh = 0; kh < 2; ++kh) {
            acc = __builtin_amdgcn_mfma_f32_16x16x32_bf16(whi[kh], xhi[kh], acc, 0, 0, 0);
            acc = __builtin_amdgcn_mfma_f32_16x16x32_bf16(wlo[kh], xhi[kh], acc, 0, 0, 0);
            acc = __builtin_amdgcn_mfma_f32_16x16x32_bf16(whi[kh], xlo[kh], acc, 0, 0, 0);
        }
        const int c0 = dt * 16 + g * 4;         // 4 consecutive features
        const float4 b4 = *(const float4*)(bias + c0);
        const float sc = (m == 0) ? QSCALE : 1.0f;
        b4v pv;
        pv[0] = (__bf16)((acc[0] + b4.x) * sc);
        pv[1] = (__bf16)((acc[1] + b4.y) * sc);
        pv[2] = (__bf16)((acc[2] + b4.z) * sc);
        pv[3] = (__bf16)((acc[3] + b4.w) * sc);
        if (m == 0) {
            *(b4v*)(Qb + (rb + r) * DM + c0) = pv;
        } else {
            const int row = rb + r, t = row >> 5, row32 = row & 31;
            const int ch  = dt * 2 + (g >> 1);
            const int b2  = ((row32 >> 4) << 1) | (ch >> 2);
            *(b4v*)(Ks + t * 2048 + b2 * 512 + (ch & 3) * 128
                       + (row32 & 15) * 8 + (g & 1) * 4) = pv;
        }
    }

    // ---- V (m=2): mfma(X, W) -> D[x-row(kv)][feat] ----
    {
        bfrag whi[2], wlo[2];
        #pragma unroll
        for (int kh = 0; kh < 2; ++kh)
            split8(wv + (dt * 16 + r) * DM + kh * 32 + g * 8, whi[kh], wlo[kh]);
        f4 acc = {0.f, 0.f, 0.f, 0.f};
        #pragma unroll
        for (int kh = 0; kh < 2; ++kh) {
            acc = __builtin_amdgcn_mfma_f32_16x16x32_bf16(xhi[kh], whi[kh], acc, 0, 0, 0);
            acc = __builtin_amdgcn_mfma_f32_16x16x32_bf16(xlo[kh], whi[kh], acc, 0, 0, 0);
            acc = __builtin_amdgcn_mfma_f32_16x16x32_bf16(xhi[kh], wlo[kh], acc, 0, 0, 0);
        }
        const int d  = dt * 16 + r;
        const float bd = bv[d];
        const int L0 = (rb & 31) + g * 4;       // kv rows rb + g*4 + e
        const int P0 = ((L0 & 15) >> 2) * 8 + (L0 >> 4) * 4;  // sigma slot base
        const int t  = rb >> 5;
        b4v pv;
        pv[0] = (__bf16)(acc[0] + bd);
        pv[1] = (__bf16)(acc[1] + bd);
        pv[2] = (__bf16)(acc[2] + bd);
        pv[3] = (__bf16)(acc[3] + bd);
        *(b4v*)(Vg + t * 2048 + (d >> 4) * 512 + (P0 >> 3) * 128
                   + (d & 15) * 8 + (P0 & 7)) = pv;
    }
}

// ---------------------------------------------------------------------------
// Kernel 2: flash attention partials — r14/r22-verified best. Barrier-free
// main loop, direct tile-major K/V loads, ones-MFMA row-sum, cvtpk pack,
// diagonal peel, 4-way balanced qt map. 1024 blocks = fam x 4 kv-slices.
// ---------------------------------------------------------------------------
__global__ __launch_bounds__(256)
__attribute__((amdgpu_waves_per_eu(4)))
void flash_attn(
    const __bf16* __restrict__ Qb, const __bf16* __restrict__ Ks,
    const __bf16* __restrict__ Vg,
    float* __restrict__ Opart, float* __restrict__ Lpart)
{
    __shared__ __align__(16) unsigned char smem[34816];  // epilogue only

    const int tid  = threadIdx.x;
    const int lane = tid & 63;
    const int wid  = tid >> 6;               // 0..3
    const int b    = blockIdx.x;
    const int fam  = b >> 2;                 // 0..255
    const int g4   = b & 3;                  // kv slice
    const int grp  = fam >> 6, hh = fam & 63;
    const int qt   = (grp == 0) ? (255 - hh) : (grp == 1) ? hh
                   : (grp == 2) ? (191 - hh) : (64 + hh);   // 4-way balanced
    const int qbase = qt * 32;
    const int gq = lane >> 4;                // 0..3
    const int r  = lane & 15;
    const int lo16 = lane << 4;

    bfrag qf[2][2];
    #pragma unroll
    for (int sub = 0; sub < 2; ++sub)
        #pragma unroll
        for (int kh = 0; kh < 2; ++kh)
            qf[sub][kh] = *(const bfrag*)(Qb + (qbase + sub * 16 + r) * DM + kh * 32 + gq * 8);

    bfrag ones;                              // B-operand of the row-sum MFMA
    #pragma unroll
    for (int e = 0; e < 8; ++e) ones[e] = (__bf16)1.0f;

    f4 o[2][4] = {};
    f4 lsacc[2] = {};                        // row-sums via MFMA (all cols equal)

    const char* Kbb = (const char*)Ks;
    const char* Vbb = (const char*)Vg;

    const int jw = g4 * 4 + wid;             // this wave's first tile
    const int nlive = (qt >= jw) ? ((qt - jw) >> 4) + 1 : 0;

    for (int s = 0; s < nlive; ++s) {
        const int j = jw + s * 16;           // uniform per wave, always live
        const long long jb = (long long)j * 4096;
        const bfrag kf0 = *(const bfrag*)(Kbb + jb + lo16);
        const bfrag kf1 = *(const bfrag*)(Kbb + jb + 1024 + lo16);
        const bfrag kf2 = *(const bfrag*)(Kbb + jb + 2048 + lo16);
        const bfrag kf3 = *(const bfrag*)(Kbb + jb + 3072 + lo16);
        bfrag vf[4];
        #pragma unroll
        for (int dt = 0; dt < 4; ++dt)
            vf[dt] = *(const bfrag*)(Vbb + jb + dt * 1024 + lo16);

        const int kvb = j * 32 + gq * 4;
        #pragma unroll
        for (int sub = 0; sub < 2; ++sub) {
            f4 sh0 = {}, sh1 = {};           // S'[kv][q], swapped operands
            sh0 = __builtin_amdgcn_mfma_f32_16x16x32_bf16(kf0, qf[sub][0], sh0, 0, 0, 0);
            sh0 = __builtin_amdgcn_mfma_f32_16x16x32_bf16(kf1, qf[sub][1], sh0, 0, 0, 0);
            sh1 = __builtin_amdgcn_mfma_f32_16x16x32_bf16(kf2, qf[sub][0], sh1, 0, 0, 0);
            sh1 = __builtin_amdgcn_mfma_f32_16x16x32_bf16(kf3, qf[sub][1], sh1, 0, 0, 0);

            float p0[4], p1[4];
            if (j < qt) {                    // interior tile: bare exp
                #pragma unroll
                for (int e = 0; e < 4; ++e) {
                    p0[e] = fexp2(sh0[e]);
                    p1[e] = fexp2(sh1[e]);
                }
            } else {                         // diagonal tile: per-element kv<=q
                const int qg = qbase + sub * 16 + r;
                #pragma unroll
                for (int e = 0; e < 4; ++e) {
                    p0[e] = (kvb + e      <= qg) ? fexp2(sh0[e]) : 0.f;
                    p1[e] = (kvb + e + 16 <= qg) ? fexp2(sh1[e]) : 0.f;
                }
            }

            PW pu;                           // sigma pack: slots 0-3 <- h0, 4-7 <- h1
            pu.w[0] = cvtpk(p0[0], p0[1]); pu.w[1] = cvtpk(p0[2], p0[3]);
            pu.w[2] = cvtpk(p1[0], p1[1]); pu.w[3] = cvtpk(p1[2], p1[3]);

            lsacc[sub] = __builtin_amdgcn_mfma_f32_16x16x32_bf16(pu.v, ones, lsacc[sub], 0, 0, 0);
            #pragma unroll
            for (int dt = 0; dt < 4; ++dt)
                o[sub][dt] = __builtin_amdgcn_mfma_f32_16x16x32_bf16(pu.v, vf[dt], o[sub][dt], 0, 0, 0);
        }
    }

    // ---- epilogue: combine 4 waves' partials (single barrier) ----
    float* Ol  = (float*)smem;               // [4][32][66] = 33792 B
    float* Lsm = (float*)(smem + 33792);     // [4][32]
    #pragma unroll
    for (int sub = 0; sub < 2; ++sub) {
        if (r == 0)
            #pragma unroll
            for (int e = 0; e < 4; ++e)
                Lsm[wid * 32 + sub * 16 + gq * 4 + e] = lsacc[sub][e];
        #pragma unroll
        for (int dt = 0; dt < 4; ++dt)
            #pragma unroll
            for (int e = 0; e < 4; ++e)
                Ol[(wid * 32 + sub * 16 + gq * 4 + e) * 66 + dt * 16 + r] = o[sub][dt][e];
    }
    __syncthreads();

    for (int i = tid; i < 32 * 64; i += 256) {
        const int row = i >> 6, col = i & 63;
        const float sum = Ol[(row) * 66 + col] + Ol[(32 + row) * 66 + col]
                        + Ol[(64 + row) * 66 + col] + Ol[(96 + row) * 66 + col];
        Opart[((long long)g4 * SEQ + qbase + row) * DM + col] = sum;
    }
    if (tid < 32) {
        const float l = Lsm[tid] + Lsm[32 + tid] + Lsm[64 + tid] + Lsm[96 + tid];
        Lpart[g4 * SEQ + qbase + tid] = l;
    }
}

// ---------------------------------------------------------------------------
// Kernel 3: out = (O0+O1+O2+O3) / (L0+L1+L2+L3)
// ---------------------------------------------------------------------------
__global__ __launch_bounds__(256) void normalize(
    const float* __restrict__ Opart, const float* __restrict__ Lpart,
    float* __restrict__ out)
{
    const int i = blockIdx.x * 256 + threadIdx.x;     // f4 index
    const f4* O = (const f4*)Opart;
    const int N = SEQ * DM / 4;
    const int row = i >> 4;
    const f4 a0 = O[i], a1 = O[N + i], a2 = O[2 * N + i], a3 = O[3 * N + i];
    const float l = (Lpart[row] + Lpart[SEQ + row])
                  + (Lpart[2 * SEQ + row] + Lpart[3 * SEQ + row]);
    const float inv = 1.0f / l;
    f4 res;
    #pragma unroll
    for (int e = 0; e < 4; ++e) res[e] = ((a0[e] + a1[e]) + (a2[e] + a3[e])) * inv;
    ((f4*)out)[i] = res;
}

extern "C" void kernel_launch(void* const* d_in, const int* in_sizes, int n_in,
                              void* d_out, int out_size, void* d_ws, size_t ws_size,
                              hipStream_t stream)
{
    (void)in_sizes; (void)n_in; (void)out_size; (void)ws_size;
    const float* x  = (const float*)d_in[0];
    const float* wq = (const float*)d_in[1];
    const float* bq = (const float*)d_in[2];
    const float* wk = (const float*)d_in[3];
    const float* bk = (const float*)d_in[4];
    const float* wv = (const float*)d_in[5];
    const float* bv = (const float*)d_in[6];
    float* out = (float*)d_out;

    __bf16* Qb = (__bf16*)d_ws;                       // [S][64] bf16, 1 MB
    __bf16* Ks = Qb + SEQ * DM;                       // tile-major K, 1 MB
    __bf16* Vg = Ks + SEQ * DM;                       // tile-major sigma V, 1 MB
    float*  Opart = (float*)(Vg + SEQ * DM);          // [4][S][64] f32, 8 MB
    float*  Lpart = Opart + 4 * SEQ * DM;             // [4][S] f32, 128 KB

    qkv_proj<<<512, 256, 0, stream>>>(x, wq, bq, wk, bk, wv, bv, Qb, Ks, Vg);
    flash_attn<<<1024, 256, 0, stream>>>(Qb, Ks, Vg, Opart, Lpart);
    normalize<<<SEQ * DM / 4 / 256, 256, 0, stream>>>(Opart, Lpart, out);
}